// Round 13
// baseline (423.920 us; speedup 1.0000x reference)
//
#include <hip/hip_runtime.h>
#include <hip/hip_bf16.h>

#define B_    64
#define S_    1024
#define CIN   5
#define K_    4
#define H1    64
#define H2    16
#define OUT_  32
#define L1_   1021      // S - K + 1
#define C1    22        // H2 + CIN + 1
#define C1SQ  484
#define SIGC1 506       // C1 + C1*C1
#define L2_   1018      // L1 - K + 1
#define SIGC2 272       // H2 + H2*H2
#define NCH   32        // sig2 time chunks
#define CH1   32        // sig2 steps per chunk

typedef __attribute__((ext_vector_type(8))) short short8;
typedef __attribute__((ext_vector_type(16))) float f32x16;

__device__ __forceinline__ unsigned short f2bf(float v) {
  __hip_bfloat16 h = __float2bfloat16(v);
  return *reinterpret_cast<unsigned short*>(&h);
}
__device__ __forceinline__ float bf2f(unsigned short u) {
  __hip_bfloat16 h;
  *reinterpret_cast<unsigned short*>(&h) = u;
  return __bfloat162float(h);
}

// ---------------- Kernel A+W: augment1 (blocks x<4) with LDS-staged weights, wt2 pack (x>=4) --------
__global__ __launch_bounds__(256) void aug1wt_kernel(
    const float* __restrict__ x,
    const float* __restrict__ w0, const float* __restrict__ b0,
    const float* __restrict__ w1, const float* __restrict__ b1,
    const float* __restrict__ w2, const float* __restrict__ b2,
    float* __restrict__ h,
    const float* __restrict__ a2w0,
    unsigned short* __restrict__ bhi, unsigned short* __restrict__ blo) {
  int tid = threadIdx.x;
  if (blockIdx.x >= 4) {
    // ---- wt2 branch: pack a2_w0 into B-fragment order, bf16 hi/lo ----
    int idx = (((blockIdx.x - 4) * B_ + blockIdx.y)) * 256 + tid;
    if (idx >= 2 * 128 * 64 * 8) return;
    int e = idx & 7;
    int lane = (idx >> 3) & 63;
    int ksg = (idx >> 9) & 127;
    int ot = idx >> 16;
    int j = ksg >> 5, cc = (ksg >> 2) & 7, ks = ksg & 3;
    int o = ot * 32 + (lane & 31);
    int c = cc * 64 + ks * 16 + (lane >> 5) * 8 + e;
    float v = (c < SIGC1) ? a2w0[o * (SIGC1 * K_) + c * K_ + j] : 0.f;
    unsigned short hb16 = f2bf(v);
    bhi[idx] = hb16;
    blo[idx] = f2bf(v - bf2f(hb16));
    return;
  }
  // ---- aug1 branch ----
  __shared__ float w0s[CIN * K_ * H1];   // indexed [o*20 + c*4 + j]
  __shared__ float w1s[H1 * H1];
  __shared__ float w2s[H2 * H1];
  __shared__ float b0s[H1], b1s[H1], b2s[H2];
  for (int i = tid; i < H1 * CIN * K_; i += 256) w0s[i] = w0[i];
  for (int i = tid; i < H1 * H1; i += 256) w1s[i] = w1[i];
  for (int i = tid; i < H2 * H1; i += 256) w2s[i] = w2[i];
  if (tid < H1) { b0s[tid] = b0[tid]; b1s[tid] = b1[tid]; }
  if (tid < H2) b2s[tid] = b2[tid];
  __syncthreads();

  int b = blockIdx.y;
  int l = blockIdx.x * 256 + tid;
  if (l >= L1_) return;
  const float* xb = x + (size_t)b * S_ * CIN;

  float t1[H1];
#pragma unroll
  for (int o = 0; o < H1; ++o) t1[o] = b0s[o];
  for (int j = 0; j < K_; ++j) {
    for (int c = 0; c < CIN; ++c) {
      float xv = xb[(l + j) * CIN + c];
#pragma unroll
      for (int o = 0; o < H1; ++o) t1[o] += xv * w0s[o * (CIN * K_) + c * K_ + j];
    }
  }
#pragma unroll
  for (int o = 0; o < H1; ++o) t1[o] = fmaxf(t1[o], 0.f);

  float t3[H2];
#pragma unroll
  for (int q = 0; q < H2; ++q) t3[q] = b2s[q];
  for (int ch = 0; ch < 4; ++ch) {
    float t2c[16];
    for (int oc = 0; oc < 16; ++oc) {
      int o = ch * 16 + oc;
      float a = b1s[o];
#pragma unroll
      for (int i = 0; i < H1; ++i) a += t1[i] * w1s[o * H1 + i];
      t2c[oc] = fmaxf(a, 0.f);
    }
#pragma unroll
    for (int q = 0; q < H2; ++q) {
      float a = t3[q];
#pragma unroll
      for (int oc = 0; oc < 16; ++oc) a += t2c[oc] * w2s[q * H1 + ch * 16 + oc];
      t3[q] = a;
    }
  }

  float* hr = h + ((size_t)b * L1_ + l) * C1;
#pragma unroll
  for (int c = 0; c < CIN; ++c) hr[c] = xb[(l + K_ - 1) * CIN + c];
  hr[CIN] = (float)l / (float)(L1_ - 1);
#pragma unroll
  for (int q = 0; q < H2; ++q) hr[CIN + 1 + q] = t3[q];
}

// ---------------- sig1a: per-(b, 256-row tile) chunk totals (tiles 0..2; tile 3 prefix unused) ------
__global__ __launch_bounds__(512) void sig1a_kernel(const float* __restrict__ h, float* __restrict__ tot1) {
  int kt = blockIdx.x, b = blockIdx.y;   // kt 0..2
  int tid = threadIdx.x;
  if (tid >= C1SQ) return;
  int start = kt * 256;
  const float* hb = h + (size_t)b * L1_ * C1;
  int i = tid / C1, j = tid - i * C1;
  float hpi = 0.f, hpj = 0.f;
  if (kt > 0) {
    hpi = hb[(start - 1) * C1 + i];
    hpj = hb[(start - 1) * C1 + j];
  }
  float pi = 0.f, pj = 0.f, s2 = 0.f;
  for (int t = start; t < start + 256; ++t) {
    float ci = hb[t * C1 + i] - hpi;
    float cj = hb[t * C1 + j] - hpj;
    float dj = cj - pj;
    s2 += pi * dj + 0.5f * (ci - pi) * dj;
    pi = ci;
    pj = cj;
  }
  tot1[((size_t)b * 4 + kt) * C1SQ + tid] = s2;
}

// ---------------- Kernel C: fused sig1-stream + MFMA conv + pointwise convs -> h2 (R10 exact) -------
// Block (k, b): 256 output rows l0=k*256. Per chunk cc (64 channels): generate the swizzled bf16 hi/lo
// A-tile IN LDS from the h tile (Chen: v = s2pre + hp_i*P[t][j] + s2loc[t]), stage B via
// global_load_lds, then MFMA + fused pw epilogue.
// LDS map (K-loop): hs f32[265][22] @0 (23320->23552) | Ah [264][128] @23552 | Al @57344 |
//                   Bs @91136 (65536) | gsum f32[512] @156672 | s2pl f32[484] @158720 -> 160768
// LDS map (epilogue, reuse): t1s f32[256][65] @0 (66560), t2s @66560, wl @133120 (20KB)
__global__ __launch_bounds__(512) void conv2pw_kernel(
    const float* __restrict__ h, const float* __restrict__ tot1,
    const unsigned short* __restrict__ bpkhi, const unsigned short* __restrict__ bpklo,
    const float* __restrict__ b0,
    const float* __restrict__ w1, const float* __restrict__ b1,
    const float* __restrict__ w2, const float* __restrict__ b2,
    float* __restrict__ h2) {
  __shared__ __align__(16) char smem[160768];
  int tid = threadIdx.x;
  int lane = tid & 63, w = tid >> 6;   // w == time-group g for generation
  int wm = w >> 1, wo = w & 1;
  int k = blockIdx.x, b = blockIdx.y, l0 = k * 256;
  const float* hb = h + (size_t)b * L1_ * C1;
  const char* bhg = (const char*)bpkhi;
  const char* blg = (const char*)bpklo;
  float* hs = (float*)smem;                       // [265][22]
  char* Ah = smem + 23552;
  char* Al = smem + 57344;
  char* Bs = smem + 91136;
  float* gsum = (float*)(smem + 156672);          // [8][64] (g-major)
  float* s2pl = (float*)(smem + 158720);          // [484]

  // ---- prologue: stage h tile rows l0-1 .. l0+263 (clamped), row 0 = basepoint ----
  for (int idx = tid; idx < 265 * C1; idx += 512) {
    int r = idx / C1, c = idx - r * C1;
    float v = 0.f;
    if (!(k == 0 && r == 0)) {
      int hr = l0 - 1 + r;
      if (hr > L1_ - 1) hr = L1_ - 1;
      v = hb[hr * C1 + c];
    }
    hs[idx] = v;
  }
  // ---- per-channel tile prefix s2pre via Chen over preceding 256-row tiles ----
  if (tid < C1SQ) {
    int i = tid / C1, j = tid - i * C1;
    float s2pv = 0.f;
    for (int kp = 0; kp < k; ++kp) {
      float bvi = 0.f, bvj = 0.f;
      if (kp > 0) {
        bvi = hb[(256 * kp - 1) * C1 + i];
        bvj = hb[(256 * kp - 1) * C1 + j];
      }
      float bv1j = hb[(256 * (kp + 1) - 1) * C1 + j];
      s2pv += bvi * (bv1j - bvj) + tot1[((size_t)b * 4 + kp) * C1SQ + tid];
    }
    s2pl[tid] = s2pv;
  }
  __syncthreads();

  f32x16 a0HH = {}, a0HL = {}, a0LH = {}, a1HH = {}, a1HL = {}, a1LH = {};
  int khalf = lane >> 5;
  int r0 = 64 * wm + (lane & 31);

  for (int cc = 0; cc < 8; ++cc) {
    if (cc) __syncthreads();   // previous chunk's MFMA done before overwriting Ah/Al/Bs/gsum
    // ---- stage B (in flight during generation) ----
    for (int s = w; s < 64; s += 8) {
      int p = s >> 2, ot = (s >> 1) & 1, plane = s & 1;
      int jj = p >> 2, ks = p & 3;
      int ksg = jj * 32 + cc * 4 + ks;
      const char* src = (plane ? blg : bhg) + (size_t)(ot * 128 + ksg) * 1024 + lane * 16;
      __builtin_amdgcn_global_load_lds(
          (const __attribute__((address_space(1))) void*)src,
          (__attribute__((address_space(3))) void*)(Bs + ((p * 2 + ot) * 2 + plane) * 1024), 16, 0, 0);
    }
    // ---- generate A chunk: channel c = cc*64 + lane, time-group g = w (33 rows each) ----
    int c = cc * 64 + lane;
    bool isS2 = (c >= C1 && c < SIGC1);
    int ii = 0, jj2 = 0;
    if (isS2) {
      int idx = c - C1;
      ii = idx / C1;
      jj2 = idx - ii * C1;
    }
    float hpi = hs[ii], hpj = hs[jj2];
    int u0 = w * 33;
    // phase 1: group partial sum of depth-2 terms
    {
      float pi = hs[u0 * C1 + ii] - hpi;     // P[u0-1]
      float pj = hs[u0 * C1 + jj2] - hpj;
      float loc = 0.f;
#pragma unroll 3
      for (int s = 0; s < 33; ++s) {
        int u = u0 + s;
        float ci = hs[(u + 1) * C1 + ii] - hpi;
        float cj = hs[(u + 1) * C1 + jj2] - hpj;
        float dj = cj - pj;
        loc += pi * dj + 0.5f * (ci - pi) * dj;
        pi = ci;
        pj = cj;
      }
      gsum[w * 64 + lane] = loc;
    }
    __syncthreads();
    // phase 2+3: exclusive prefix over groups, re-scan and emit bf16 hi/lo into swizzled LDS
    {
      float s2r = isS2 ? s2pl[c - C1] : 0.f;
      for (int gp = 0; gp < w; ++gp) s2r += gsum[gp * 64 + lane];
      float pi = hs[u0 * C1 + ii] - hpi;
      float pj = hs[u0 * C1 + jj2] - hpj;
#pragma unroll 3
      for (int s = 0; s < 33; ++s) {
        int u = u0 + s;
        float v;
        if (isS2) {
          float ci = hs[(u + 1) * C1 + ii] - hpi;
          float cj = hs[(u + 1) * C1 + jj2] - hpj;
          float dj = cj - pj;
          s2r += pi * dj + 0.5f * (ci - pi) * dj;
          pi = ci;
          pj = cj;
          v = s2r + hpi * cj;                 // Chen: A2 + A1 (x) B1 + B2
        } else if (c < C1) {
          v = hs[(u + 1) * C1 + c];           // level 1 = unshifted h[t]
        } else {
          v = 0.f;                            // pad channels 506..511
        }
        unsigned short hb16 = f2bf(v);
        unsigned short lb16 = f2bf(v - bf2f(hb16));
        int boff = u * 128 + ((((lane >> 3) ^ (u & 7))) << 4) + (lane & 7) * 2;
        *(unsigned short*)(Ah + boff) = hb16;
        *(unsigned short*)(Al + boff) = lb16;
      }
    }
    __syncthreads();   // A writes visible; B vmcnt drained
    // ---- MFMA ----
#pragma unroll
    for (int j = 0; j < 4; ++j) {
      int ra0 = r0 + j, ra1 = ra0 + 32;
      int rx0 = ra0 & 7, rx1 = ra1 & 7;
      const char* a0b = Ah + ra0 * 128;
      const char* a0bl = Al + ra0 * 128;
      const char* a1b = Ah + ra1 * 128;
      const char* a1bl = Al + ra1 * 128;
#pragma unroll
      for (int ks = 0; ks < 4; ++ks) {
        int p = j * 4 + ks;
        const char* bb = Bs + (size_t)((p * 2 + wo) * 2) * 1024 + lane * 16;
        short8 b_h = *(const short8*)bb;
        short8 b_l = *(const short8*)(bb + 1024);
        int g0 = ((ks * 2 + khalf) ^ rx0) << 4;
        int g1 = ((ks * 2 + khalf) ^ rx1) << 4;
        short8 v0h = *(const short8*)(a0b + g0);
        short8 v0l = *(const short8*)(a0bl + g0);
        short8 v1h = *(const short8*)(a1b + g1);
        short8 v1l = *(const short8*)(a1bl + g1);
        a0HH = __builtin_amdgcn_mfma_f32_32x32x16_bf16(v0h, b_h, a0HH, 0, 0, 0);
        a0HL = __builtin_amdgcn_mfma_f32_32x32x16_bf16(v0h, b_l, a0HL, 0, 0, 0);
        a0LH = __builtin_amdgcn_mfma_f32_32x32x16_bf16(v0l, b_h, a0LH, 0, 0, 0);
        a1HH = __builtin_amdgcn_mfma_f32_32x32x16_bf16(v1h, b_h, a1HH, 0, 0, 0);
        a1HL = __builtin_amdgcn_mfma_f32_32x32x16_bf16(v1h, b_l, a1HL, 0, 0, 0);
        a1LH = __builtin_amdgcn_mfma_f32_32x32x16_bf16(v1l, b_h, a1LH, 0, 0, 0);
      }
    }
  }
  __syncthreads();
  // ---- epilogue: relu(t1+b0) -> 1x1(64->64)+relu -> 1x1(64->16) -> h2 ----
  float* t1s = (float*)smem;                  // [256][65]
  float* t2s = (float*)(smem + 66560);        // [256][65]
  float* wl = (float*)(smem + 133120);        // w1 4096 f, then w2 1024 f
  for (int i2 = tid; i2 < 4096; i2 += 512) wl[i2] = w1[i2];
  for (int i2 = tid; i2 < 1024; i2 += 512) wl[4096 + i2] = w2[i2];
  {
    int col = 32 * wo + (lane & 31);
    float bbv = b0[col];
    int rbase = 64 * wm + 4 * (lane >> 5);
#pragma unroll
    for (int rg = 0; rg < 16; ++rg) {
      int row = (rg & 3) + 8 * (rg >> 2) + rbase;
      t1s[row * 65 + col] = fmaxf(a0HH[rg] + a0HL[rg] + a0LH[rg] + bbv, 0.f);
      t1s[(row + 32) * 65 + col] = fmaxf(a1HH[rg] + a1HL[rg] + a1LH[rg] + bbv, 0.f);
    }
  }
  __syncthreads();
  {
    int row = tid & 255, qh = tid >> 8;
    float tr[64];
#pragma unroll
    for (int i2 = 0; i2 < 64; ++i2) tr[i2] = t1s[row * 65 + i2];
#pragma unroll
    for (int oc = 0; oc < 32; ++oc) {
      int o = qh * 32 + oc;
      float a = b1[o];
      const float4* wr = (const float4*)(wl + o * 64);
#pragma unroll
      for (int i4 = 0; i4 < 16; ++i4) {
        float4 wv = wr[i4];
        a += tr[i4 * 4] * wv.x + tr[i4 * 4 + 1] * wv.y +
             tr[i4 * 4 + 2] * wv.z + tr[i4 * 4 + 3] * wv.w;
      }
      t2s[row * 65 + o] = fmaxf(a, 0.f);
    }
  }
  __syncthreads();
  {
    int row = tid & 255, ph = tid >> 8;
    int l = l0 + row;
    if (l < L2_) {
      float tr2[64];
#pragma unroll
      for (int i2 = 0; i2 < 64; ++i2) tr2[i2] = t2s[row * 65 + i2];
      float* outr = h2 + ((size_t)b * L2_ + l) * H2;
#pragma unroll
      for (int pp = 0; pp < 8; ++pp) {
        int pch = ph * 8 + pp;
        float a = b2[pch];
        const float4* wr = (const float4*)(wl + 4096 + pch * 64);
#pragma unroll
        for (int i4 = 0; i4 < 16; ++i4) {
          float4 wv = wr[i4];
          a += tr2[i4 * 4] * wv.x + tr2[i4 * 4 + 1] * wv.y +
               tr2[i4 * 4 + 2] * wv.z + tr2[i4 * 4 + 3] * wv.w;
        }
        outr[pch] = a;
      }
    }
  }
}

// ---------------- sig2 phase A: de-barriered per-(b,chunk) scan with become_constant clamp ----------
__global__ __launch_bounds__(256) void sig2a_kernel(const float* __restrict__ h2, const int* __restrict__ lengths,
                                                    float* __restrict__ s2tot2) {
  int k = blockIdx.x, b = blockIdx.y;
  int tid = threadIdx.x;
  int i = tid >> 4, j = tid & 15;
  int adjm1 = lengths[b] - (2 * K_ - 2) - 1;  // lengths - 7
  int start = k * CH1, end = min(start + CH1 - 1, L2_ - 1);
  size_t oidx = ((size_t)b * NCH + k) * 256 + tid;
  if (k > 0 && start - 1 >= adjm1) {
    s2tot2[oidx] = 0.f;
    return;
  }
  const float* h2b = h2 + (size_t)b * L2_ * H2;
  float hpi = 0.f, hpj = 0.f;
  if (k > 0) {
    int row = min(start - 1, adjm1);
    hpi = h2b[row * H2 + i];
    hpj = h2b[row * H2 + j];
  }
  float pi = 0.f, pj = 0.f, s2 = 0.f;
#pragma unroll 4
  for (int t = start; t <= end; ++t) {
    int row = min(t, adjm1);
    float ci = h2b[row * H2 + i] - hpi;
    float cj = h2b[row * H2 + j] - hpj;
    float dj = cj - pj;
    s2 += pi * dj + 0.5f * (ci - pi) * dj;
    pi = ci;
    pj = cj;
  }
  s2tot2[oidx] = s2;
}

// ---------------- sig2 phase B: NCH-step Chen combine + final linear -----------------
__global__ __launch_bounds__(256) void sig2b_kernel(const float* __restrict__ h2, const int* __restrict__ lengths,
                                                    const float* __restrict__ s2tot2,
                                                    const float* __restrict__ lin_w, const float* __restrict__ lin_b,
                                                    float* __restrict__ out) {
  int b = blockIdx.x;
  int tid = threadIdx.x;
  int i = tid >> 4, j = tid & 15;
  int adjm1 = lengths[b] - (2 * K_ - 2) - 1;
  const float* h2b = h2 + (size_t)b * L2_ * H2;
  __shared__ float bv[NCH + 1][H2];
  __shared__ float s2s[SIGC2];
  for (int idx = tid; idx < (NCH + 1) * H2; idx += 256) {
    int kk = idx >> 4, c = idx & 15;
    float v = 0.f;
    if (kk > 0) {
      int row = min(min(CH1 * kk - 1, L2_ - 1), adjm1);
      v = h2b[row * H2 + c];
    }
    bv[kk][c] = v;
  }
  __syncthreads();
  float s2 = 0.f;
  for (int k = 0; k < NCH; ++k) {
    s2 += bv[k][i] * (bv[k + 1][j] - bv[k][j]) + s2tot2[((size_t)b * NCH + k) * 256 + tid];
  }
  s2s[H2 + tid] = s2;
  if (tid < H2) s2s[tid] = bv[NCH][tid];
  __syncthreads();
  if (tid < OUT_) {
    float a = lin_b[tid];
    for (int c = 0; c < SIGC2; ++c) a += s2s[c] * lin_w[tid * SIGC2 + c];
    out[b * OUT_ + tid] = a;
  }
}

extern "C" void kernel_launch(void* const* d_in, const int* in_sizes, int n_in,
                              void* d_out, int out_size, void* d_ws, size_t ws_size,
                              hipStream_t stream) {
  const float* x      = (const float*)d_in[0];
  const int*   lengths= (const int*)d_in[1];
  const float* a1_w0  = (const float*)d_in[2];
  const float* a1_b0  = (const float*)d_in[3];
  const float* a1_w1  = (const float*)d_in[4];
  const float* a1_b1  = (const float*)d_in[5];
  const float* a1_w2  = (const float*)d_in[6];
  const float* a1_b2  = (const float*)d_in[7];
  const float* a2_w0  = (const float*)d_in[8];
  const float* a2_b0  = (const float*)d_in[9];
  const float* a2_w1  = (const float*)d_in[10];
  const float* a2_b1  = (const float*)d_in[11];
  const float* a2_w2  = (const float*)d_in[12];
  const float* a2_b2  = (const float*)d_in[13];
  const float* lin_w  = (const float*)d_in[14];
  const float* lin_b  = (const float*)d_in[15];
  float* outp = (float*)d_out;

  float* ws = (float*)d_ws;
  // layout (float offsets):
  float* h = ws;                                            // 1,437,568 f
  unsigned short* bpkhi = (unsigned short*)(ws + 1437568);  // 131,072 u16
  unsigned short* bpklo = bpkhi + 131072;
  float* h2 = ws + 1568640;                                 // 1,042,432 f
  float* tot1 = ws + 2611072;                               // B*4*C1SQ = 123,904 f
  float* s2tot2 = ws + 2734976;                             // B*NCH*256 = 524,288 f -> 3,259,264 f (13 MB)

  aug1wt_kernel<<<dim3(12, B_), 256, 0, stream>>>(x, a1_w0, a1_b0, a1_w1, a1_b1, a1_w2, a1_b2, h,
                                                  a2_w0, bpkhi, bpklo);
  sig1a_kernel<<<dim3(3, B_), 512, 0, stream>>>(h, tot1);
  conv2pw_kernel<<<dim3(4, B_), 512, 0, stream>>>(h, tot1, bpkhi, bpklo, a2_b0,
                                                  a2_w1, a2_b1, a2_w2, a2_b2, h2);
  sig2a_kernel<<<dim3(NCH, B_), 256, 0, stream>>>(h2, lengths, s2tot2);
  sig2b_kernel<<<B_, 256, 0, stream>>>(h2, lengths, s2tot2, lin_w, lin_b, outp);
}

// Round 14
// 257.807 us; speedup vs baseline: 1.6443x; 1.6443x over previous
//
#include <hip/hip_runtime.h>
#include <hip/hip_bf16.h>

#define B_    64
#define S_    1024
#define CIN   5
#define K_    4
#define H1    64
#define H2    16
#define OUT_  32
#define L1_   1021      // S - K + 1
#define C1    22        // H2 + CIN + 1
#define C1SQ  484
#define SIGC1 506       // C1 + C1*C1
#define L2_   1018      // L1 - K + 1
#define SIGC2 272       // H2 + H2*H2
#define NCH   32        // sig2 time chunks
#define CH1   32        // sig2 steps per chunk

typedef __attribute__((ext_vector_type(8))) short short8;
typedef __attribute__((ext_vector_type(16))) float f32x16;

__device__ __forceinline__ unsigned short f2bf(float v) {
  __hip_bfloat16 h = __float2bfloat16(v);
  return *reinterpret_cast<unsigned short*>(&h);
}
__device__ __forceinline__ float bf2f(unsigned short u) {
  __hip_bfloat16 h;
  *reinterpret_cast<unsigned short*>(&h) = u;
  return __bfloat162float(h);
}

// ---------------- Kernel A: augment1 (R10 exact) ----------
__global__ __launch_bounds__(256) void aug1_kernel(
    const float* __restrict__ x,
    const float* __restrict__ w0, const float* __restrict__ b0,
    const float* __restrict__ w1, const float* __restrict__ b1,
    const float* __restrict__ w2, const float* __restrict__ b2,
    float* __restrict__ h) {
  int b = blockIdx.y;
  int l = blockIdx.x * 256 + threadIdx.x;
  if (l >= L1_) return;
  const float* xb = x + (size_t)b * S_ * CIN;

  float t1[H1];
#pragma unroll
  for (int o = 0; o < H1; ++o) t1[o] = b0[o];
  for (int j = 0; j < K_; ++j) {
    for (int c = 0; c < CIN; ++c) {
      float xv = xb[(l + j) * CIN + c];
#pragma unroll
      for (int o = 0; o < H1; ++o) t1[o] += xv * w0[o * (CIN * K_) + c * K_ + j];
    }
  }
#pragma unroll
  for (int o = 0; o < H1; ++o) t1[o] = fmaxf(t1[o], 0.f);

  float t3[H2];
#pragma unroll
  for (int q = 0; q < H2; ++q) t3[q] = b2[q];
  for (int ch = 0; ch < 4; ++ch) {
    float t2c[16];
    for (int oc = 0; oc < 16; ++oc) {
      int o = ch * 16 + oc;
      float a = b1[o];
#pragma unroll
      for (int i = 0; i < H1; ++i) a += t1[i] * w1[o * H1 + i];
      t2c[oc] = fmaxf(a, 0.f);
    }
#pragma unroll
    for (int q = 0; q < H2; ++q) {
      float a = t3[q];
#pragma unroll
      for (int oc = 0; oc < 16; ++oc) a += t2c[oc] * w2[q * H1 + ch * 16 + oc];
      t3[q] = a;
    }
  }

  float* hr = h + ((size_t)b * L1_ + l) * C1;
#pragma unroll
  for (int c = 0; c < CIN; ++c) hr[c] = xb[(l + K_ - 1) * CIN + c];
  hr[CIN] = (float)l / (float)(L1_ - 1);
#pragma unroll
  for (int q = 0; q < H2; ++q) hr[CIN + 1 + q] = t3[q];
}

// ---------------- Kernel WS: merged wt2 pack + sig1a (both light; saves one launch) ----------------
// blocks [0,192): sig1a  kt=blk/64 (0..2), b=blk%64 — per-(b, 256-row tile) chunk totals
// blocks [192,448): wt2  idx=(blk-192)*512+tid — pack a2_w0 into B-fragment order, bf16 hi/lo
__global__ __launch_bounds__(512) void wtsig_kernel(
    const float* __restrict__ h, float* __restrict__ tot1,
    const float* __restrict__ a2w0,
    unsigned short* __restrict__ bhi, unsigned short* __restrict__ blo) {
  int blk = blockIdx.x;
  int tid = threadIdx.x;
  if (blk >= 192) {
    int idx = (blk - 192) * 512 + tid;   // < 2*128*64*8 = 131072 exactly
    int e = idx & 7;
    int lane = (idx >> 3) & 63;
    int ksg = (idx >> 9) & 127;
    int ot = idx >> 16;
    int j = ksg >> 5, cc = (ksg >> 2) & 7, ks = ksg & 3;
    int o = ot * 32 + (lane & 31);
    int c = cc * 64 + ks * 16 + (lane >> 5) * 8 + e;
    float v = (c < SIGC1) ? a2w0[o * (SIGC1 * K_) + c * K_ + j] : 0.f;
    unsigned short hb16 = f2bf(v);
    bhi[idx] = hb16;
    blo[idx] = f2bf(v - bf2f(hb16));
    return;
  }
  if (tid >= C1SQ) return;
  int kt = blk / 64, b = blk - kt * 64;
  int start = kt * 256;
  const float* hb = h + (size_t)b * L1_ * C1;
  int i = tid / C1, j = tid - i * C1;
  float hpi = 0.f, hpj = 0.f;
  if (kt > 0) {
    hpi = hb[(start - 1) * C1 + i];
    hpj = hb[(start - 1) * C1 + j];
  }
  float pi = 0.f, pj = 0.f, s2 = 0.f;
  for (int t = start; t < start + 256; ++t) {
    float ci = hb[t * C1 + i] - hpi;
    float cj = hb[t * C1 + j] - hpj;
    float dj = cj - pj;
    s2 += pi * dj + 0.5f * (ci - pi) * dj;
    pi = ci;
    pj = cj;
  }
  tot1[((size_t)b * 4 + kt) * C1SQ + tid] = s2;
}

// ---------------- Kernel C: fused sig1-stream + MFMA conv + pointwise convs -> h2 (R10 exact) -------
// Block (k, b): 256 output rows l0=k*256. Per chunk cc (64 channels): generate the swizzled bf16 hi/lo
// A-tile IN LDS from the h tile (Chen: v = s2pre + hp_i*P[t][j] + s2loc[t]), stage B via
// global_load_lds, then MFMA + fused pw epilogue.
// LDS map (K-loop): hs f32[265][22] @0 (23320->23552) | Ah [264][128] @23552 | Al @57344 |
//                   Bs @91136 (65536) | gsum f32[512] @156672 | s2pl f32[484] @158720 -> 160768
// LDS map (epilogue, reuse): t1s f32[256][65] @0 (66560), t2s @66560, wl @133120 (20KB)
__global__ __launch_bounds__(512) void conv2pw_kernel(
    const float* __restrict__ h, const float* __restrict__ tot1,
    const unsigned short* __restrict__ bpkhi, const unsigned short* __restrict__ bpklo,
    const float* __restrict__ b0,
    const float* __restrict__ w1, const float* __restrict__ b1,
    const float* __restrict__ w2, const float* __restrict__ b2,
    float* __restrict__ h2) {
  __shared__ __align__(16) char smem[160768];
  int tid = threadIdx.x;
  int lane = tid & 63, w = tid >> 6;   // w == time-group g for generation
  int wm = w >> 1, wo = w & 1;
  int k = blockIdx.x, b = blockIdx.y, l0 = k * 256;
  const float* hb = h + (size_t)b * L1_ * C1;
  const char* bhg = (const char*)bpkhi;
  const char* blg = (const char*)bpklo;
  float* hs = (float*)smem;                       // [265][22]
  char* Ah = smem + 23552;
  char* Al = smem + 57344;
  char* Bs = smem + 91136;
  float* gsum = (float*)(smem + 156672);          // [8][64] (g-major)
  float* s2pl = (float*)(smem + 158720);          // [484]

  // ---- prologue: stage h tile rows l0-1 .. l0+263 (clamped), row 0 = basepoint ----
  for (int idx = tid; idx < 265 * C1; idx += 512) {
    int r = idx / C1, c = idx - r * C1;
    float v = 0.f;
    if (!(k == 0 && r == 0)) {
      int hr = l0 - 1 + r;
      if (hr > L1_ - 1) hr = L1_ - 1;
      v = hb[hr * C1 + c];
    }
    hs[idx] = v;
  }
  // ---- per-channel tile prefix s2pre via Chen over preceding 256-row tiles ----
  if (tid < C1SQ) {
    int i = tid / C1, j = tid - i * C1;
    float s2pv = 0.f;
    for (int kp = 0; kp < k; ++kp) {
      float bvi = 0.f, bvj = 0.f;
      if (kp > 0) {
        bvi = hb[(256 * kp - 1) * C1 + i];
        bvj = hb[(256 * kp - 1) * C1 + j];
      }
      float bv1j = hb[(256 * (kp + 1) - 1) * C1 + j];
      s2pv += bvi * (bv1j - bvj) + tot1[((size_t)b * 4 + kp) * C1SQ + tid];
    }
    s2pl[tid] = s2pv;
  }
  __syncthreads();

  f32x16 a0HH = {}, a0HL = {}, a0LH = {}, a1HH = {}, a1HL = {}, a1LH = {};
  int khalf = lane >> 5;
  int r0 = 64 * wm + (lane & 31);

  for (int cc = 0; cc < 8; ++cc) {
    if (cc) __syncthreads();   // previous chunk's MFMA done before overwriting Ah/Al/Bs/gsum
    // ---- stage B (in flight during generation) ----
    for (int s = w; s < 64; s += 8) {
      int p = s >> 2, ot = (s >> 1) & 1, plane = s & 1;
      int jj = p >> 2, ks = p & 3;
      int ksg = jj * 32 + cc * 4 + ks;
      const char* src = (plane ? blg : bhg) + (size_t)(ot * 128 + ksg) * 1024 + lane * 16;
      __builtin_amdgcn_global_load_lds(
          (const __attribute__((address_space(1))) void*)src,
          (__attribute__((address_space(3))) void*)(Bs + ((p * 2 + ot) * 2 + plane) * 1024), 16, 0, 0);
    }
    // ---- generate A chunk: channel c = cc*64 + lane, time-group g = w (33 rows each) ----
    int c = cc * 64 + lane;
    bool isS2 = (c >= C1 && c < SIGC1);
    int ii = 0, jj2 = 0;
    if (isS2) {
      int idx = c - C1;
      ii = idx / C1;
      jj2 = idx - ii * C1;
    }
    float hpi = hs[ii], hpj = hs[jj2];
    int u0 = w * 33;
    // phase 1: group partial sum of depth-2 terms
    {
      float pi = hs[u0 * C1 + ii] - hpi;     // P[u0-1]
      float pj = hs[u0 * C1 + jj2] - hpj;
      float loc = 0.f;
#pragma unroll 3
      for (int s = 0; s < 33; ++s) {
        int u = u0 + s;
        float ci = hs[(u + 1) * C1 + ii] - hpi;
        float cj = hs[(u + 1) * C1 + jj2] - hpj;
        float dj = cj - pj;
        loc += pi * dj + 0.5f * (ci - pi) * dj;
        pi = ci;
        pj = cj;
      }
      gsum[w * 64 + lane] = loc;
    }
    __syncthreads();
    // phase 2+3: exclusive prefix over groups, re-scan and emit bf16 hi/lo into swizzled LDS
    {
      float s2r = isS2 ? s2pl[c - C1] : 0.f;
      for (int gp = 0; gp < w; ++gp) s2r += gsum[gp * 64 + lane];
      float pi = hs[u0 * C1 + ii] - hpi;
      float pj = hs[u0 * C1 + jj2] - hpj;
#pragma unroll 3
      for (int s = 0; s < 33; ++s) {
        int u = u0 + s;
        float v;
        if (isS2) {
          float ci = hs[(u + 1) * C1 + ii] - hpi;
          float cj = hs[(u + 1) * C1 + jj2] - hpj;
          float dj = cj - pj;
          s2r += pi * dj + 0.5f * (ci - pi) * dj;
          pi = ci;
          pj = cj;
          v = s2r + hpi * cj;                 // Chen: A2 + A1 (x) B1 + B2
        } else if (c < C1) {
          v = hs[(u + 1) * C1 + c];           // level 1 = unshifted h[t]
        } else {
          v = 0.f;                            // pad channels 506..511
        }
        unsigned short hb16 = f2bf(v);
        unsigned short lb16 = f2bf(v - bf2f(hb16));
        int boff = u * 128 + ((((lane >> 3) ^ (u & 7))) << 4) + (lane & 7) * 2;
        *(unsigned short*)(Ah + boff) = hb16;
        *(unsigned short*)(Al + boff) = lb16;
      }
    }
    __syncthreads();   // A writes visible; B vmcnt drained
    // ---- MFMA ----
#pragma unroll
    for (int j = 0; j < 4; ++j) {
      int ra0 = r0 + j, ra1 = ra0 + 32;
      int rx0 = ra0 & 7, rx1 = ra1 & 7;
      const char* a0b = Ah + ra0 * 128;
      const char* a0bl = Al + ra0 * 128;
      const char* a1b = Ah + ra1 * 128;
      const char* a1bl = Al + ra1 * 128;
#pragma unroll
      for (int ks = 0; ks < 4; ++ks) {
        int p = j * 4 + ks;
        const char* bb = Bs + (size_t)((p * 2 + wo) * 2) * 1024 + lane * 16;
        short8 b_h = *(const short8*)bb;
        short8 b_l = *(const short8*)(bb + 1024);
        int g0 = ((ks * 2 + khalf) ^ rx0) << 4;
        int g1 = ((ks * 2 + khalf) ^ rx1) << 4;
        short8 v0h = *(const short8*)(a0b + g0);
        short8 v0l = *(const short8*)(a0bl + g0);
        short8 v1h = *(const short8*)(a1b + g1);
        short8 v1l = *(const short8*)(a1bl + g1);
        a0HH = __builtin_amdgcn_mfma_f32_32x32x16_bf16(v0h, b_h, a0HH, 0, 0, 0);
        a0HL = __builtin_amdgcn_mfma_f32_32x32x16_bf16(v0h, b_l, a0HL, 0, 0, 0);
        a0LH = __builtin_amdgcn_mfma_f32_32x32x16_bf16(v0l, b_h, a0LH, 0, 0, 0);
        a1HH = __builtin_amdgcn_mfma_f32_32x32x16_bf16(v1h, b_h, a1HH, 0, 0, 0);
        a1HL = __builtin_amdgcn_mfma_f32_32x32x16_bf16(v1h, b_l, a1HL, 0, 0, 0);
        a1LH = __builtin_amdgcn_mfma_f32_32x32x16_bf16(v1l, b_h, a1LH, 0, 0, 0);
      }
    }
  }
  __syncthreads();
  // ---- epilogue: relu(t1+b0) -> 1x1(64->64)+relu -> 1x1(64->16) -> h2 ----
  float* t1s = (float*)smem;                  // [256][65]
  float* t2s = (float*)(smem + 66560);        // [256][65]
  float* wl = (float*)(smem + 133120);        // w1 4096 f, then w2 1024 f
  for (int i2 = tid; i2 < 4096; i2 += 512) wl[i2] = w1[i2];
  for (int i2 = tid; i2 < 1024; i2 += 512) wl[4096 + i2] = w2[i2];
  {
    int col = 32 * wo + (lane & 31);
    float bbv = b0[col];
    int rbase = 64 * wm + 4 * (lane >> 5);
#pragma unroll
    for (int rg = 0; rg < 16; ++rg) {
      int row = (rg & 3) + 8 * (rg >> 2) + rbase;
      t1s[row * 65 + col] = fmaxf(a0HH[rg] + a0HL[rg] + a0LH[rg] + bbv, 0.f);
      t1s[(row + 32) * 65 + col] = fmaxf(a1HH[rg] + a1HL[rg] + a1LH[rg] + bbv, 0.f);
    }
  }
  __syncthreads();
  {
    int row = tid & 255, qh = tid >> 8;
    float tr[64];
#pragma unroll
    for (int i2 = 0; i2 < 64; ++i2) tr[i2] = t1s[row * 65 + i2];
#pragma unroll
    for (int oc = 0; oc < 32; ++oc) {
      int o = qh * 32 + oc;
      float a = b1[o];
      const float4* wr = (const float4*)(wl + o * 64);
#pragma unroll
      for (int i4 = 0; i4 < 16; ++i4) {
        float4 wv = wr[i4];
        a += tr[i4 * 4] * wv.x + tr[i4 * 4 + 1] * wv.y +
             tr[i4 * 4 + 2] * wv.z + tr[i4 * 4 + 3] * wv.w;
      }
      t2s[row * 65 + o] = fmaxf(a, 0.f);
    }
  }
  __syncthreads();
  {
    int row = tid & 255, ph = tid >> 8;
    int l = l0 + row;
    if (l < L2_) {
      float tr2[64];
#pragma unroll
      for (int i2 = 0; i2 < 64; ++i2) tr2[i2] = t2s[row * 65 + i2];
      float* outr = h2 + ((size_t)b * L2_ + l) * H2;
#pragma unroll
      for (int pp = 0; pp < 8; ++pp) {
        int pch = ph * 8 + pp;
        float a = b2[pch];
        const float4* wr = (const float4*)(wl + 4096 + pch * 64);
#pragma unroll
        for (int i4 = 0; i4 < 16; ++i4) {
          float4 wv = wr[i4];
          a += tr2[i4 * 4] * wv.x + tr2[i4 * 4 + 1] * wv.y +
               tr2[i4 * 4 + 2] * wv.z + tr2[i4 * 4 + 3] * wv.w;
        }
        outr[pch] = a;
      }
    }
  }
}

// ---------------- sig2 phase A: de-barriered per-(b,chunk) scan with become_constant clamp ----------
__global__ __launch_bounds__(256) void sig2a_kernel(const float* __restrict__ h2, const int* __restrict__ lengths,
                                                    float* __restrict__ s2tot2) {
  int k = blockIdx.x, b = blockIdx.y;
  int tid = threadIdx.x;
  int i = tid >> 4, j = tid & 15;
  int adjm1 = lengths[b] - (2 * K_ - 2) - 1;  // lengths - 7
  int start = k * CH1, end = min(start + CH1 - 1, L2_ - 1);
  size_t oidx = ((size_t)b * NCH + k) * 256 + tid;
  if (k > 0 && start - 1 >= adjm1) {
    s2tot2[oidx] = 0.f;
    return;
  }
  const float* h2b = h2 + (size_t)b * L2_ * H2;
  float hpi = 0.f, hpj = 0.f;
  if (k > 0) {
    int row = min(start - 1, adjm1);
    hpi = h2b[row * H2 + i];
    hpj = h2b[row * H2 + j];
  }
  float pi = 0.f, pj = 0.f, s2 = 0.f;
#pragma unroll 4
  for (int t = start; t <= end; ++t) {
    int row = min(t, adjm1);
    float ci = h2b[row * H2 + i] - hpi;
    float cj = h2b[row * H2 + j] - hpj;
    float dj = cj - pj;
    s2 += pi * dj + 0.5f * (ci - pi) * dj;
    pi = ci;
    pj = cj;
  }
  s2tot2[oidx] = s2;
}

// ---------------- sig2 phase B: NCH-step Chen combine + final linear -----------------
__global__ __launch_bounds__(256) void sig2b_kernel(const float* __restrict__ h2, const int* __restrict__ lengths,
                                                    const float* __restrict__ s2tot2,
                                                    const float* __restrict__ lin_w, const float* __restrict__ lin_b,
                                                    float* __restrict__ out) {
  int b = blockIdx.x;
  int tid = threadIdx.x;
  int i = tid >> 4, j = tid & 15;
  int adjm1 = lengths[b] - (2 * K_ - 2) - 1;
  const float* h2b = h2 + (size_t)b * L2_ * H2;
  __shared__ float bv[NCH + 1][H2];
  __shared__ float s2s[SIGC2];
  for (int idx = tid; idx < (NCH + 1) * H2; idx += 256) {
    int kk = idx >> 4, c = idx & 15;
    float v = 0.f;
    if (kk > 0) {
      int row = min(min(CH1 * kk - 1, L2_ - 1), adjm1);
      v = h2b[row * H2 + c];
    }
    bv[kk][c] = v;
  }
  __syncthreads();
  float s2 = 0.f;
  for (int k = 0; k < NCH; ++k) {
    s2 += bv[k][i] * (bv[k + 1][j] - bv[k][j]) + s2tot2[((size_t)b * NCH + k) * 256 + tid];
  }
  s2s[H2 + tid] = s2;
  if (tid < H2) s2s[tid] = bv[NCH][tid];
  __syncthreads();
  if (tid < OUT_) {
    float a = lin_b[tid];
    for (int c = 0; c < SIGC2; ++c) a += s2s[c] * lin_w[tid * SIGC2 + c];
    out[b * OUT_ + tid] = a;
  }
}

extern "C" void kernel_launch(void* const* d_in, const int* in_sizes, int n_in,
                              void* d_out, int out_size, void* d_ws, size_t ws_size,
                              hipStream_t stream) {
  const float* x      = (const float*)d_in[0];
  const int*   lengths= (const int*)d_in[1];
  const float* a1_w0  = (const float*)d_in[2];
  const float* a1_b0  = (const float*)d_in[3];
  const float* a1_w1  = (const float*)d_in[4];
  const float* a1_b1  = (const float*)d_in[5];
  const float* a1_w2  = (const float*)d_in[6];
  const float* a1_b2  = (const float*)d_in[7];
  const float* a2_w0  = (const float*)d_in[8];
  const float* a2_b0  = (const float*)d_in[9];
  const float* a2_w1  = (const float*)d_in[10];
  const float* a2_b1  = (const float*)d_in[11];
  const float* a2_w2  = (const float*)d_in[12];
  const float* a2_b2  = (const float*)d_in[13];
  const float* lin_w  = (const float*)d_in[14];
  const float* lin_b  = (const float*)d_in[15];
  float* outp = (float*)d_out;

  float* ws = (float*)d_ws;
  // layout (float offsets):
  float* h = ws;                                            // 1,437,568 f
  unsigned short* bpkhi = (unsigned short*)(ws + 1437568);  // 131,072 u16
  unsigned short* bpklo = bpkhi + 131072;
  float* h2 = ws + 1568640;                                 // 1,042,432 f
  float* tot1 = ws + 2611072;                               // B*4*C1SQ = 123,904 f
  float* s2tot2 = ws + 2734976;                             // B*NCH*256 = 524,288 f -> 3,259,264 f (13 MB)

  aug1_kernel<<<dim3(4, B_), 256, 0, stream>>>(x, a1_w0, a1_b0, a1_w1, a1_b1, a1_w2, a1_b2, h);
  wtsig_kernel<<<448, 512, 0, stream>>>(h, tot1, a2_w0, bpkhi, bpklo);
  conv2pw_kernel<<<dim3(4, B_), 512, 0, stream>>>(h, tot1, bpkhi, bpklo, a2_b0,
                                                  a2_w1, a2_b1, a2_w2, a2_b2, h2);
  sig2a_kernel<<<dim3(NCH, B_), 256, 0, stream>>>(h2, lengths, s2tot2);
  sig2b_kernel<<<B_, 256, 0, stream>>>(h2, lengths, s2tot2, lin_w, lin_b, outp);
}